// Round 9
// baseline (1411.596 us; speedup 1.0000x reference)
//
#include <hip/hip_runtime.h>

// Problem constants (reference: T=64 time steps, B=SEQ=128 batch, IN=256, H=512)
#define TT 64
#define BB 128
#define IND 256
#define HH 512
#define GG 2048      // 4*H
#define NCC 10
#define KFLAT 65536  // SEQ*H
#define HP2 520      // bf16 LDS row stride (512 + 8)

typedef __attribute__((ext_vector_type(8))) short bf16x8;
typedef __attribute__((ext_vector_type(4))) float floatx4;

__device__ __forceinline__ unsigned short f2bf(float x) {   // RNE round to bf16
    unsigned u = __builtin_bit_cast(unsigned, x);
    u += 0x7fffu + ((u >> 16) & 1u);
    return (unsigned short)(u >> 16);
}
__device__ __forceinline__ float bf2f(unsigned short h) {
    unsigned u = ((unsigned)h) << 16;
    return __builtin_bit_cast(float, u);
}
__device__ __forceinline__ float pk2f(unsigned u) {
    float hi = __builtin_bit_cast(float, u & 0xffff0000u);
    float lo = __builtin_bit_cast(float, u << 16);
    return hi + lo;
}

// ---------------------------------------------------------------------------
// Stage 8 tagged h-cells into LDS hi/lo planes — ATOMIC (coherence-point)
// path. Retry fallback only; returns nonzero on tag miss.
// ---------------------------------------------------------------------------
__device__ __forceinline__ unsigned stage8_atomic(
    const unsigned long long* __restrict__ src, int bb, int kk, unsigned exp,
    short (*Hs_hi)[HP2], short (*Hs_lo)[HP2])
{
    unsigned long long q0 = __hip_atomic_load(src + 0, __ATOMIC_RELAXED, __HIP_MEMORY_SCOPE_AGENT);
    unsigned long long q1 = __hip_atomic_load(src + 1, __ATOMIC_RELAXED, __HIP_MEMORY_SCOPE_AGENT);
    unsigned long long q2 = __hip_atomic_load(src + 2, __ATOMIC_RELAXED, __HIP_MEMORY_SCOPE_AGENT);
    unsigned long long q3 = __hip_atomic_load(src + 3, __ATOMIC_RELAXED, __HIP_MEMORY_SCOPE_AGENT);
    unsigned c0 = (unsigned)q0, c1 = (unsigned)(q0 >> 32);
    unsigned c2 = (unsigned)q1, c3 = (unsigned)(q1 >> 32);
    unsigned c4 = (unsigned)q2, c5 = (unsigned)(q2 >> 32);
    unsigned c6 = (unsigned)q3, c7 = (unsigned)(q3 >> 32);
    unsigned bad = ((c0 ^ exp) | (c1 ^ exp) | (c2 ^ exp) | (c3 ^ exp)
                  | (c4 ^ exp) | (c5 ^ exp) | (c6 ^ exp) | (c7 ^ exp)) & 0xFu;
    uint4 hiv, lov;
    hiv.x = (c0 >> 16) | (c1 & 0xffff0000u);
    hiv.y = (c2 >> 16) | (c3 & 0xffff0000u);
    hiv.z = (c4 >> 16) | (c5 & 0xffff0000u);
    hiv.w = (c6 >> 16) | (c7 & 0xffff0000u);
    lov.x = (c0 & 0xFFF0u) | ((c1 & 0xFFF0u) << 16);
    lov.y = (c2 & 0xFFF0u) | ((c3 & 0xFFF0u) << 16);
    lov.z = (c4 & 0xFFF0u) | ((c5 & 0xFFF0u) << 16);
    lov.w = (c6 & 0xFFF0u) | ((c7 & 0xFFF0u) << 16);
    *(uint4*)&Hs_hi[bb][kk] = hiv;
    *(uint4*)&Hs_lo[bb][kk] = lov;
    return bad;
}

// ---------------------------------------------------------------------------
// Stage 8 tagged h-cells — PLAIN CACHED path (fast). Only issued after the
// flag handshake; tag check retained, mismatch retried via stage8_atomic.
// ---------------------------------------------------------------------------
__device__ __forceinline__ unsigned stage8_plain(
    const unsigned* __restrict__ src, int bb, int kk, unsigned exp,
    short (*Hs_hi)[HP2], short (*Hs_lo)[HP2])
{
    const uint4 v0 = *(const uint4*)(src);
    const uint4 v1 = *(const uint4*)(src + 4);
    unsigned bad = ((v0.x ^ exp) | (v0.y ^ exp) | (v0.z ^ exp) | (v0.w ^ exp)
                  | (v1.x ^ exp) | (v1.y ^ exp) | (v1.z ^ exp) | (v1.w ^ exp)) & 0xFu;
    uint4 hiv, lov;
    hiv.x = (v0.x >> 16) | (v0.y & 0xffff0000u);
    hiv.y = (v0.z >> 16) | (v0.w & 0xffff0000u);
    hiv.z = (v1.x >> 16) | (v1.y & 0xffff0000u);
    hiv.w = (v1.z >> 16) | (v1.w & 0xffff0000u);
    lov.x = (v0.x & 0xFFF0u) | ((v0.y & 0xFFF0u) << 16);
    lov.y = (v0.z & 0xFFF0u) | ((v0.w & 0xFFF0u) << 16);
    lov.z = (v1.x & 0xFFF0u) | ((v1.y & 0xFFF0u) << 16);
    lov.w = (v1.z & 0xFFF0u) | ((v1.w & 0xFFF0u) << 16);
    *(uint4*)&Hs_hi[bb][kk] = hiv;
    *(uint4*)&Hs_lo[bb][kk] = lov;
    return bad;
}

// Tile stage: plain cached pass + atomic retry fallback (R5-proven).
__device__ __forceinline__ void stage_tile_g(
    const unsigned* __restrict__ base, unsigned exp,
    int tstart, int pcount, int pstride,
    short (*Hs_hi)[HP2], short (*Hs_lo)[HP2])
{
    unsigned miss = 0;
    for (int p = 0; p < pcount; ++p) {
        const int idx = p * pstride + tstart;
        unsigned bad = stage8_plain(base + idx, idx >> 9, idx & 511,
                                    exp, Hs_hi, Hs_lo);
        miss |= (bad ? 1u : 0u) << p;
    }
    while (miss) {
        for (int p = 0; p < pcount; ++p) {
            if (miss & (1u << p)) {
                const int idx = p * pstride + tstart;
                if (!stage8_atomic((const unsigned long long*)(base + idx),
                                   idx >> 9, idx & 511, exp, Hs_hi, Hs_lo))
                    miss &= ~(1u << p);
            }
        }
    }
}

// Agent-scope relaxed poll (R5-proven). BOUNDED: flags are a latency
// optimization only; tag-retry staging is a complete correctness protocol.
__device__ __forceinline__ void spin_flag(const unsigned* p) {
    int n = 0;
    while (__hip_atomic_load(p, __ATOMIC_RELAXED, __HIP_MEMORY_SCOPE_AGENT) == 0u) {
        if (++n > 65536) break;
    }
}

// ---------------------------------------------------------------------------
// FUSED two-layer persistent LSTM — R9: layer-0 input GEMM folded into the
// idle X-waves (the entire xg precompute pipeline is deleted).
//
// Blocks 0..127 = layer 0; 128..255 = layer 1. WG (bt, jsl): batches
// [bt*32,+32) x 16 hidden units. 512 threads: waves 0-3 = R pipeline
// (poll fR, stage Ra, R-MFMA, update, tagged h store, flag), waves 4-7 =
// X pipeline: layer-1 computes Wih1*h0[t+1] (flag-gated, tag-checked);
// layer-0 computes Wih0*x[t] — x is a plain kernel input, so its staging
// needs NO polls and NO tags (fp32 -> split-bf16 conversion into LDS).
// Update sums GsR + GsX + (b_ih + b_hh) for BOTH layers.
//
// Sync protocol = byte-exact R5 (the measured local optimum): tagged
// relaxed-agent h stores (per-cell 4B), B4 barrier drain, single tid0
// relaxed-agent flag store; consumers: wave0 polls 32 R-flags / wave4
// polls 32 X-flags (layer 1), B1, then plain cached staging with tag
// check + atomic retry. Tags (lo nibble, gen%9) are the correctness net;
// 0xA harness poison never matches a tag.
// ---------------------------------------------------------------------------
__global__ __launch_bounds__(512, 2) void lstm_fused(
    const float* __restrict__ x,      // [T][B][IN] fp32 input
    const float* __restrict__ w_hh0,  // [4H][H] fp32
    const float* __restrict__ w_ih0,  // [4H][IN] fp32
    const float* __restrict__ w_ih1,  // [4H][H] fp32
    const float* __restrict__ w_hh1,  // [4H][H] fp32
    const float* __restrict__ b_ih0, const float* __restrict__ b_hh0,
    const float* __restrict__ b_ih1, const float* __restrict__ b_hh1,
    unsigned* __restrict__ hpack0,    // [T+1][B][H] tagged, block 0 zeroed
    unsigned* __restrict__ hpack1,    // [T+1][B][H] tagged, block 0 zeroed
    unsigned* __restrict__ flags)     // [2][T+1][4][32] step flags (zeroed)
{
    __shared__ short Ra_hi[32][HP2], Ra_lo[32][HP2];   // recurrent h tile
    __shared__ short Xa_hi[32][HP2], Xa_lo[32][HP2];   // X-input tile (h0 or x)
    __shared__ float GsR[64][33];
    __shared__ float GsX[64][33];

    const int tid  = threadIdx.x;          // 0..511
    const int lane = tid & 63;
    const int wv   = tid >> 6;             // 0..7
    const bool isR = wv < 4;               // R-pipeline waves
    const int gate = wv & 3;               // gate for MFMA (both roles)
    const bool isB = blockIdx.x >= 128;
    const int blk  = blockIdx.x & 127;
    const int bt   = blk & 3;
    const int jsl  = blk >> 2;             // producer j-slice id 0..31
    const int j0   = jsl * 16;             // 16-unit slice
    const int l15  = lane & 15;
    const int quad = lane >> 4;
    const int tid_x = tid - 256;           // X-thread linear id (valid if !isR)

    // ---- preload weight frags: ONE array per thread, role-dependent ----
    // R-threads: w_hh (K=512, 16 frags). Layer-1 X: w_ih1 (K=512, 16 frags).
    // Layer-0 X: w_ih0 (K=256, 8 frags).
    bf16x8 wf_hi[16], wf_lo[16];
    {
        const float* wsrc;
        int kstride, nfrag;
        if (isR)      { wsrc = isB ? w_hh1 : w_hh0; kstride = HH;  nfrag = 16; }
        else if (isB) { wsrc = w_ih1;               kstride = HH;  nfrag = 16; }
        else          { wsrc = w_ih0;               kstride = IND; nfrag = 8;  }
        const float* wrow = wsrc + (size_t)(gate * HH + j0 + l15) * kstride + quad * 8;
        for (int kc = 0; kc < nfrag; ++kc) {
            float f[8];
            *(float4*)&f[0] = *(const float4*)&wrow[kc * 32];
            *(float4*)&f[4] = *(const float4*)&wrow[kc * 32 + 4];
            bf16x8 vh, vl;
            #pragma unroll
            for (int j = 0; j < 8; ++j) {
                unsigned short hb = f2bf(f[j]);
                vh[j] = (short)hb;
                vl[j] = (short)f2bf(f[j] - bf2f(hb));
            }
            wf_hi[kc] = vh; wf_lo[kc] = vl;
        }
    }

    // update-phase roles (R-threads): cells (j_u, bu) and (j_u, bu+16)
    const int j_u = tid & 15;
    const int bu  = (tid >> 4) & 15;       // 0..15
    float bias_i = 0.f, bias_f = 0.f, bias_g = 0.f, bias_o = 0.f;
    if (isR) {
        const float* bA = isB ? b_ih1 : b_ih0;
        const float* bB = isB ? b_hh1 : b_hh0;
        bias_i = bA[j0 + j_u]            + bB[j0 + j_u];
        bias_f = bA[HH + j0 + j_u]       + bB[HH + j0 + j_u];
        bias_g = bA[2 * HH + j0 + j_u]   + bB[2 * HH + j0 + j_u];
        bias_o = bA[3 * HH + j0 + j_u]   + bB[3 * HH + j0 + j_u];
    }

    unsigned* hp_rec = isB ? hpack1 : hpack0;
    const int layerBase = isB ? 65 : 0;
    float c0 = 0.f, c1 = 0.f;

    for (int t = 0; t < TT; ++t) {
        const unsigned* rec_base = hp_rec + (size_t)t * (BB * HH) + (size_t)bt * 32 * HH;
        const unsigned* inp_base = hpack0 + (size_t)(t + 1) * (BB * HH) + (size_t)bt * 32 * HH;
        const unsigned expR = (unsigned)t % 9u;
        const unsigned expX = (unsigned)(t + 1) % 9u;
        const unsigned* fR = flags + ((layerBase + t) * 4 + bt) * 32;
        const unsigned* fX = flags + ((t + 1) * 4 + bt) * 32;

        // ---- polls: wave 0 -> 32 R-flags; wave 4 -> 32 X-flags (layer 1).
        //      Layer-0's X input x[t] is a plain kernel input: no poll. ----
        if (wv == 0 && lane < 32 && t > 0 && lane != jsl) spin_flag(fR + lane);
        if (isB && wv == 4 && lane < 32) spin_flag(fX + lane);
        __syncthreads();                                   // B1

        // ---- staging ----
        if (isR) {
            stage_tile_g(rec_base, expR, tid * 8, 8, 2048, Ra_hi, Ra_lo);
        } else if (isB) {
            stage_tile_g(inp_base, expX, tid_x * 8, 8, 2048, Xa_hi, Xa_lo);
        } else {
            // layer-0 X: stage x[t] (32 rows x 256 fp32) as split-bf16.
            // No tags (input data). 256 threads x 32 values each.
            const int row = tid_x >> 3;
            const int cb  = (tid_x & 7) * 32;
            const float* src = x + (size_t)t * (BB * IND)
                             + (size_t)(bt * 32 + row) * IND + cb;
            #pragma unroll
            for (int q = 0; q < 4; ++q) {
                float f[8];
                *(float4*)&f[0] = *(const float4*)&src[q * 8];
                *(float4*)&f[4] = *(const float4*)&src[q * 8 + 4];
                short hs[8], ls[8];
                #pragma unroll
                for (int j = 0; j < 8; ++j) {
                    unsigned short hb = f2bf(f[j]);
                    hs[j] = (short)hb;
                    ls[j] = (short)f2bf(f[j] - bf2f(hb));
                }
                *(uint4*)&Xa_hi[row][cb + q * 8] = *(const uint4*)hs;
                *(uint4*)&Xa_lo[row][cb + q * 8] = *(const uint4*)ls;
            }
        }
        __syncthreads();                                   // B2

        // ---- MFMA + Gs writes ----
        if (isR) {
            floatx4 a0 = {0.f,0.f,0.f,0.f}, a1 = {0.f,0.f,0.f,0.f};
            #pragma unroll
            for (int kc = 0; kc < 16; ++kc) {
                const int off = kc * 32 + quad * 8;
                bf16x8 r0h = *(const bf16x8*)&Ra_hi[l15][off];
                bf16x8 r0l = *(const bf16x8*)&Ra_lo[l15][off];
                bf16x8 r1h = *(const bf16x8*)&Ra_hi[16 + l15][off];
                bf16x8 r1l = *(const bf16x8*)&Ra_lo[16 + l15][off];
                a0 = __builtin_amdgcn_mfma_f32_16x16x32_bf16(wf_hi[kc], r0h, a0, 0, 0, 0);
                a1 = __builtin_amdgcn_mfma_f32_16x16x32_bf16(wf_hi[kc], r1h, a1, 0, 0, 0);
                a0 = __builtin_amdgcn_mfma_f32_16x16x32_bf16(wf_hi[kc], r0l, a0, 0, 0, 0);
                a1 = __builtin_amdgcn_mfma_f32_16x16x32_bf16(wf_hi[kc], r1l, a1, 0, 0, 0);
                a0 = __builtin_amdgcn_mfma_f32_16x16x32_bf16(wf_lo[kc], r0h, a0, 0, 0, 0);
                a1 = __builtin_amdgcn_mfma_f32_16x16x32_bf16(wf_lo[kc], r1h, a1, 0, 0, 0);
            }
            #pragma unroll
            for (int r = 0; r < 4; ++r) {
                GsR[gate * 16 + quad * 4 + r][l15]      = a0[r];
                GsR[gate * 16 + quad * 4 + r][16 + l15] = a1[r];
            }
        } else {
            const int nkc = isB ? 16 : 8;
            floatx4 a0 = {0.f,0.f,0.f,0.f}, a1 = {0.f,0.f,0.f,0.f};
            for (int kc = 0; kc < nkc; ++kc) {
                const int off = kc * 32 + quad * 8;
                bf16x8 x0h = *(const bf16x8*)&Xa_hi[l15][off];
                bf16x8 x0l = *(const bf16x8*)&Xa_lo[l15][off];
                bf16x8 x1h = *(const bf16x8*)&Xa_hi[16 + l15][off];
                bf16x8 x1l = *(const bf16x8*)&Xa_lo[16 + l15][off];
                a0 = __builtin_amdgcn_mfma_f32_16x16x32_bf16(wf_hi[kc], x0h, a0, 0, 0, 0);
                a1 = __builtin_amdgcn_mfma_f32_16x16x32_bf16(wf_hi[kc], x1h, a1, 0, 0, 0);
                a0 = __builtin_amdgcn_mfma_f32_16x16x32_bf16(wf_hi[kc], x0l, a0, 0, 0, 0);
                a1 = __builtin_amdgcn_mfma_f32_16x16x32_bf16(wf_hi[kc], x1l, a1, 0, 0, 0);
                a0 = __builtin_amdgcn_mfma_f32_16x16x32_bf16(wf_lo[kc], x0h, a0, 0, 0, 0);
                a1 = __builtin_amdgcn_mfma_f32_16x16x32_bf16(wf_lo[kc], x1h, a1, 0, 0, 0);
            }
            #pragma unroll
            for (int r = 0; r < 4; ++r) {
                GsX[gate * 16 + quad * 4 + r][l15]      = a0[r];
                GsX[gate * 16 + quad * 4 + r][16 + l15] = a1[r];
            }
        }
        __syncthreads();                                   // B3

        // ---- update (R-threads): 2 cells; tagged per-cell 4B stores ----
        if (isR) {
            const unsigned tag = (unsigned)(t + 1) % 9u;
            #pragma unroll
            for (int ccell = 0; ccell < 2; ++ccell) {
                const int b = bu + ccell * 16;
                float gi = GsR[j_u][b]      + GsX[j_u][b]      + bias_i;
                float gf = GsR[16 + j_u][b] + GsX[16 + j_u][b] + bias_f;
                float gg = GsR[32 + j_u][b] + GsX[32 + j_u][b] + bias_g;
                float go = GsR[48 + j_u][b] + GsX[48 + j_u][b] + bias_o;
                const float si = 1.f / (1.f + __expf(-gi));
                const float sf = 1.f / (1.f + __expf(-gf));
                const float tg = 2.f / (1.f + __expf(-2.f * gg)) - 1.f;
                const float so = 1.f / (1.f + __expf(-go));
                float& cr = ccell ? c1 : c0;
                cr = sf * cr + si * tg;
                const float th = 2.f / (1.f + __expf(-2.f * cr)) - 1.f;
                const float hval = so * th;
                const unsigned short hb = f2bf(hval);
                const unsigned short lb = f2bf(hval - bf2f(hb));
                const unsigned pk = ((unsigned)hb << 16) | ((unsigned)lb & 0xFFF0u) | tag;
                __hip_atomic_store(
                    &hp_rec[(size_t)(t + 1) * (BB * HH) + (size_t)(bt * 32 + b) * HH + j0 + j_u],
                    pk, __ATOMIC_RELAXED, __HIP_MEMORY_SCOPE_AGENT);
            }
        }
        __syncthreads();                                   // B4 (drains stores)

        // ---- publish: single flag store for this slice (R5-proven) ----
        if (tid == 0)
            __hip_atomic_store(
                flags + ((layerBase + (t + 1)) * 4 + bt) * 32 + jsl,
                1u, __ATOMIC_RELAXED, __HIP_MEMORY_SCOPE_AGENT);
    }
}

// ---------------------------------------------------------------------------
// Classifier split-K partial GEMM on tagged h cells (mask tag nibble)
// ---------------------------------------------------------------------------
__global__ __launch_bounds__(256) void cls_partial_kernel(
    const unsigned* __restrict__ A, const float* __restrict__ W,
    float* __restrict__ part)
{
    const int n0 = blockIdx.x * 64;
    const int s  = blockIdx.y;
    const int kbase = s * 2048;
    const int tid = threadIdx.x;
    __shared__ float As[32][68];
    __shared__ float Bs[32][68];
    const int tm = tid >> 4, tn = tid & 15;
    float acc[4][4] = {};

    for (int kt = 0; kt < 2048; kt += 32) {
        #pragma unroll
        for (int q = tid; q < 512; q += 256) {
            const int mm = q >> 3;
            const int kq = q & 7;
            uint4 v = *(const uint4*)&A[(size_t)mm * KFLAT + kbase + kt + kq * 4];
            As[kq*4+0][mm] = pk2f(v.x & 0xFFFFFFF0u); As[kq*4+1][mm] = pk2f(v.y & 0xFFFFFFF0u);
            As[kq*4+2][mm] = pk2f(v.z & 0xFFFFFFF0u); As[kq*4+3][mm] = pk2f(v.w & 0xFFFFFFF0u);
            float4 w = *(const float4*)&W[(size_t)(n0 + mm) * KFLAT + kbase + kt + kq * 4];
            Bs[kq*4+0][mm] = w.x; Bs[kq*4+1][mm] = w.y;
            Bs[kq*4+2][mm] = w.z; Bs[kq*4+3][mm] = w.w;
        }
        __syncthreads();
        #pragma unroll
        for (int k = 0; k < 32; ++k) {
            float4 a = *(const float4*)&As[k][tm * 4];
            float4 b = *(const float4*)&Bs[k][tn * 4];
            acc[0][0] += a.x*b.x; acc[0][1] += a.x*b.y; acc[0][2] += a.x*b.z; acc[0][3] += a.x*b.w;
            acc[1][0] += a.y*b.x; acc[1][1] += a.y*b.y; acc[1][2] += a.y*b.z; acc[1][3] += a.y*b.w;
            acc[2][0] += a.z*b.x; acc[2][1] += a.z*b.y; acc[2][2] += a.z*b.z; acc[2][3] += a.z*b.w;
            acc[3][0] += a.w*b.x; acc[3][1] += a.w*b.y; acc[3][2] += a.w*b.z; acc[3][3] += a.w*b.w;
        }
        __syncthreads();
    }
    #pragma unroll
    for (int i = 0; i < 4; ++i) {
        const int m = tm * 4 + i;
        #pragma unroll
        for (int j = 0; j < 4; ++j) {
            part[((size_t)s * 64 + m) * 512 + n0 + tn * 4 + j] = acc[i][j];
        }
    }
}

// ---------------------------------------------------------------------------
// Classifier finish (unchanged)
// ---------------------------------------------------------------------------
__global__ __launch_bounds__(256) void cls_final_kernel(
    const float* __restrict__ part, const float* __restrict__ b1,
    const float* __restrict__ w2, const float* __restrict__ b2,
    float* __restrict__ out)
{
    const int t = blockIdx.x;
    __shared__ float hm[512];
    for (int n = threadIdx.x; n < 512; n += 256) {
        float sacc = b1[n];
        for (int sl = 0; sl < 32; ++sl)
            sacc += part[((size_t)sl * 64 + t) * 512 + n];
        hm[n] = fmaxf(sacc, 0.f);
    }
    __syncthreads();
    if (threadIdx.x < NCC) {
        float sacc = b2[threadIdx.x];
        const float* wr = w2 + (size_t)threadIdx.x * 512;
        for (int n = 0; n < 512; ++n) sacc += hm[n] * wr[n];
        out[t * NCC + threadIdx.x] = sacc;
    }
}

// ---------------------------------------------------------------------------
extern "C" void kernel_launch(void* const* d_in, const int* in_sizes, int n_in,
                              void* d_out, int out_size, void* d_ws, size_t ws_size,
                              hipStream_t stream)
{
    const float* x     = (const float*)d_in[0];
    const float* w_ih0 = (const float*)d_in[1];
    const float* w_hh0 = (const float*)d_in[2];
    const float* b_ih0 = (const float*)d_in[3];
    const float* b_hh0 = (const float*)d_in[4];
    const float* w_ih1 = (const float*)d_in[5];
    const float* w_hh1 = (const float*)d_in[6];
    const float* b_ih1 = (const float*)d_in[7];
    const float* b_hh1 = (const float*)d_in[8];
    const float* w1    = (const float*)d_in[9];
    const float* b1    = (const float*)d_in[10];
    const float* w2    = (const float*)d_in[11];
    const float* b2    = (const float*)d_in[12];
    float* out = (float*)d_out;

    // Workspace (~38.1 MB): the entire xg/xpk/w0pk precompute path is gone
    // (layer-0 input GEMM fused into lstm_fused's X-waves). All t>=1 h
    // reads are flag-gated (flags zeroed each launch) and tag-checked.
    // flags alias the part region (part written only after lstm_fused).
    unsigned* hpack0 = (unsigned*)d_ws;                         // 17.04 MB
    unsigned* hpack1 = hpack0 + (size_t)65 * BB * HH;           // 17.04 MB
    float*    part   = (float*)(hpack1 + (size_t)65 * BB * HH); // 4 MB
    unsigned* flags  = (unsigned*)part;                         // 66.6 KB (dies at cls)

    // ---- init: t=0 h blocks (tag 0 == 0%9 matches) + flags ----
    hipMemsetAsync(hpack0, 0, (size_t)BB * HH * sizeof(unsigned), stream);
    hipMemsetAsync(hpack1, 0, (size_t)BB * HH * sizeof(unsigned), stream);
    hipMemsetAsync(flags, 0, (size_t)2 * 65 * 4 * 32 * sizeof(unsigned), stream);

    // ---- fused two-layer recurrence (input GEMM folded in) ----
    lstm_fused<<<256, 512, 0, stream>>>(
        x, w_hh0, w_ih0, w_ih1, w_hh1, b_ih0, b_hh0, b_ih1, b_hh1,
        hpack0, hpack1, flags);

    // ---- classifier (tagged h1, blocks 1..64) ----
    cls_partial_kernel<<<dim3(512 / 64, 32), 256, 0, stream>>>(
        hpack1 + (size_t)BB * HH, w1, part);
    cls_final_kernel<<<64, 256, 0, stream>>>(part, b1, w2, b2, out);
}

// Round 10
// 932.438 us; speedup vs baseline: 1.5139x; 1.5139x over previous
//
#include <hip/hip_runtime.h>

// Problem constants (reference: T=64 time steps, B=SEQ=128 batch, IN=256, H=512)
#define TT 64
#define BB 128
#define IND 256
#define HH 512
#define GG 2048      // 4*H
#define NCC 10
#define KFLAT 65536  // SEQ*H
#define HP2 520      // bf16 LDS row stride (512 + 8)

typedef __attribute__((ext_vector_type(8))) short bf16x8;
typedef __attribute__((ext_vector_type(4))) float floatx4;

__device__ __forceinline__ unsigned short f2bf(float x) {   // RNE round to bf16
    unsigned u = __builtin_bit_cast(unsigned, x);
    u += 0x7fffu + ((u >> 16) & 1u);
    return (unsigned short)(u >> 16);
}
__device__ __forceinline__ float bf2f(unsigned short h) {
    unsigned u = ((unsigned)h) << 16;
    return __builtin_bit_cast(float, u);
}
__device__ __forceinline__ float pk2f(unsigned u) {
    float hi = __builtin_bit_cast(float, u & 0xffff0000u);
    float lo = __builtin_bit_cast(float, u << 16);
    return hi + lo;
}

// ---------------------------------------------------------------------------
// Weight-fragment preload with COMPILE-TIME count (rule #20: runtime-indexed
// ext_vector arrays spill to scratch — R9's 1.74GB FETCH regression).
// ---------------------------------------------------------------------------
template<int NF>
__device__ __forceinline__ void load_wfrag(
    const float* __restrict__ wrow, bf16x8* wh, bf16x8* wl)
{
    #pragma unroll
    for (int kc = 0; kc < NF; ++kc) {
        float f[8];
        *(float4*)&f[0] = *(const float4*)&wrow[kc * 32];
        *(float4*)&f[4] = *(const float4*)&wrow[kc * 32 + 4];
        bf16x8 vh, vl;
        #pragma unroll
        for (int j = 0; j < 8; ++j) {
            unsigned short hb = f2bf(f[j]);
            vh[j] = (short)hb;
            vl[j] = (short)f2bf(f[j] - bf2f(hb));
        }
        wh[kc] = vh; wl[kc] = vl;
    }
}

// MFMA sweep over an LDS tile with COMPILE-TIME frag count.
template<int NF>
__device__ __forceinline__ void mfma_sweep(
    const bf16x8* wh, const bf16x8* wl,
    const short (*Hs_hi)[HP2], const short (*Hs_lo)[HP2],
    int l15, int quad, floatx4& a0, floatx4& a1)
{
    #pragma unroll
    for (int kc = 0; kc < NF; ++kc) {
        const int off = kc * 32 + quad * 8;
        bf16x8 r0h = *(const bf16x8*)&Hs_hi[l15][off];
        bf16x8 r0l = *(const bf16x8*)&Hs_lo[l15][off];
        bf16x8 r1h = *(const bf16x8*)&Hs_hi[16 + l15][off];
        bf16x8 r1l = *(const bf16x8*)&Hs_lo[16 + l15][off];
        a0 = __builtin_amdgcn_mfma_f32_16x16x32_bf16(wh[kc], r0h, a0, 0, 0, 0);
        a1 = __builtin_amdgcn_mfma_f32_16x16x32_bf16(wh[kc], r1h, a1, 0, 0, 0);
        a0 = __builtin_amdgcn_mfma_f32_16x16x32_bf16(wh[kc], r0l, a0, 0, 0, 0);
        a1 = __builtin_amdgcn_mfma_f32_16x16x32_bf16(wh[kc], r1l, a1, 0, 0, 0);
        a0 = __builtin_amdgcn_mfma_f32_16x16x32_bf16(wl[kc], r0h, a0, 0, 0, 0);
        a1 = __builtin_amdgcn_mfma_f32_16x16x32_bf16(wl[kc], r1h, a1, 0, 0, 0);
    }
}

// ---------------------------------------------------------------------------
// Stage 8 tagged h-cells into LDS hi/lo planes — ATOMIC (coherence-point)
// path. Retry fallback only; returns nonzero on tag miss.
// ---------------------------------------------------------------------------
__device__ __forceinline__ unsigned stage8_atomic(
    const unsigned long long* __restrict__ src, int bb, int kk, unsigned exp,
    short (*Hs_hi)[HP2], short (*Hs_lo)[HP2])
{
    unsigned long long q0 = __hip_atomic_load(src + 0, __ATOMIC_RELAXED, __HIP_MEMORY_SCOPE_AGENT);
    unsigned long long q1 = __hip_atomic_load(src + 1, __ATOMIC_RELAXED, __HIP_MEMORY_SCOPE_AGENT);
    unsigned long long q2 = __hip_atomic_load(src + 2, __ATOMIC_RELAXED, __HIP_MEMORY_SCOPE_AGENT);
    unsigned long long q3 = __hip_atomic_load(src + 3, __ATOMIC_RELAXED, __HIP_MEMORY_SCOPE_AGENT);
    unsigned c0 = (unsigned)q0, c1 = (unsigned)(q0 >> 32);
    unsigned c2 = (unsigned)q1, c3 = (unsigned)(q1 >> 32);
    unsigned c4 = (unsigned)q2, c5 = (unsigned)(q2 >> 32);
    unsigned c6 = (unsigned)q3, c7 = (unsigned)(q3 >> 32);
    unsigned bad = ((c0 ^ exp) | (c1 ^ exp) | (c2 ^ exp) | (c3 ^ exp)
                  | (c4 ^ exp) | (c5 ^ exp) | (c6 ^ exp) | (c7 ^ exp)) & 0xFu;
    uint4 hiv, lov;
    hiv.x = (c0 >> 16) | (c1 & 0xffff0000u);
    hiv.y = (c2 >> 16) | (c3 & 0xffff0000u);
    hiv.z = (c4 >> 16) | (c5 & 0xffff0000u);
    hiv.w = (c6 >> 16) | (c7 & 0xffff0000u);
    lov.x = (c0 & 0xFFF0u) | ((c1 & 0xFFF0u) << 16);
    lov.y = (c2 & 0xFFF0u) | ((c3 & 0xFFF0u) << 16);
    lov.z = (c4 & 0xFFF0u) | ((c5 & 0xFFF0u) << 16);
    lov.w = (c6 & 0xFFF0u) | ((c7 & 0xFFF0u) << 16);
    *(uint4*)&Hs_hi[bb][kk] = hiv;
    *(uint4*)&Hs_lo[bb][kk] = lov;
    return bad;
}

// ---------------------------------------------------------------------------
// Stage 8 tagged h-cells — PLAIN CACHED path (fast). Only issued after the
// flag handshake; tag check retained, mismatch retried via stage8_atomic.
// ---------------------------------------------------------------------------
__device__ __forceinline__ unsigned stage8_plain(
    const unsigned* __restrict__ src, int bb, int kk, unsigned exp,
    short (*Hs_hi)[HP2], short (*Hs_lo)[HP2])
{
    const uint4 v0 = *(const uint4*)(src);
    const uint4 v1 = *(const uint4*)(src + 4);
    unsigned bad = ((v0.x ^ exp) | (v0.y ^ exp) | (v0.z ^ exp) | (v0.w ^ exp)
                  | (v1.x ^ exp) | (v1.y ^ exp) | (v1.z ^ exp) | (v1.w ^ exp)) & 0xFu;
    uint4 hiv, lov;
    hiv.x = (v0.x >> 16) | (v0.y & 0xffff0000u);
    hiv.y = (v0.z >> 16) | (v0.w & 0xffff0000u);
    hiv.z = (v1.x >> 16) | (v1.y & 0xffff0000u);
    hiv.w = (v1.z >> 16) | (v1.w & 0xffff0000u);
    lov.x = (v0.x & 0xFFF0u) | ((v0.y & 0xFFF0u) << 16);
    lov.y = (v0.z & 0xFFF0u) | ((v0.w & 0xFFF0u) << 16);
    lov.z = (v1.x & 0xFFF0u) | ((v1.y & 0xFFF0u) << 16);
    lov.w = (v1.z & 0xFFF0u) | ((v1.w & 0xFFF0u) << 16);
    *(uint4*)&Hs_hi[bb][kk] = hiv;
    *(uint4*)&Hs_lo[bb][kk] = lov;
    return bad;
}

// Tile stage: plain cached pass + atomic retry fallback (R5-proven).
__device__ __forceinline__ void stage_tile_g(
    const unsigned* __restrict__ base, unsigned exp,
    int tstart, int pcount, int pstride,
    short (*Hs_hi)[HP2], short (*Hs_lo)[HP2])
{
    unsigned miss = 0;
    for (int p = 0; p < pcount; ++p) {
        const int idx = p * pstride + tstart;
        unsigned bad = stage8_plain(base + idx, idx >> 9, idx & 511,
                                    exp, Hs_hi, Hs_lo);
        miss |= (bad ? 1u : 0u) << p;
    }
    while (miss) {
        for (int p = 0; p < pcount; ++p) {
            if (miss & (1u << p)) {
                const int idx = p * pstride + tstart;
                if (!stage8_atomic((const unsigned long long*)(base + idx),
                                   idx >> 9, idx & 511, exp, Hs_hi, Hs_lo))
                    miss &= ~(1u << p);
            }
        }
    }
}

// Agent-scope relaxed poll (R5-proven). BOUNDED: flags are a latency
// optimization only; tag-retry staging is a complete correctness protocol.
__device__ __forceinline__ void spin_flag(const unsigned* p) {
    int n = 0;
    while (__hip_atomic_load(p, __ATOMIC_RELAXED, __HIP_MEMORY_SCOPE_AGENT) == 0u) {
        if (++n > 65536) break;
    }
}

// ---------------------------------------------------------------------------
// FUSED two-layer persistent LSTM — R10: R9's fused input GEMM with the
// scratch-spill fixed (constant-bound unrolled weight loops; rule #20).
//
// Blocks 0..127 = layer 0; 128..255 = layer 1. WG (bt, jsl): batches
// [bt*32,+32) x 16 hidden units. 512 threads: waves 0-3 = R pipeline
// (poll fR, stage Ra, R-MFMA, update, tagged h store, flag), waves 4-7 =
// X pipeline: layer-1 computes Wih1*h0[t+1] (flag-gated, tag-checked);
// layer-0 computes Wih0*x[t] — x is a plain kernel input (no poll/tags).
// Update sums GsR + GsX + (b_ih + b_hh) for BOTH layers.
//
// Sync protocol = byte-exact R5 (the measured local optimum): tagged
// relaxed-agent h stores (per-cell 4B), B4 barrier drain, single tid0
// relaxed-agent flag store; consumers: wave0 polls 32 R-flags / wave4
// polls 32 X-flags (layer 1), B1, then plain cached staging with tag
// check + atomic retry. Tags (lo nibble, gen%9) are the correctness net;
// 0xA harness poison never matches a tag.
// ---------------------------------------------------------------------------
__global__ __launch_bounds__(512, 2) void lstm_fused(
    const float* __restrict__ x,      // [T][B][IN] fp32 input
    const float* __restrict__ w_hh0,  // [4H][H] fp32
    const float* __restrict__ w_ih0,  // [4H][IN] fp32
    const float* __restrict__ w_ih1,  // [4H][H] fp32
    const float* __restrict__ w_hh1,  // [4H][H] fp32
    const float* __restrict__ b_ih0, const float* __restrict__ b_hh0,
    const float* __restrict__ b_ih1, const float* __restrict__ b_hh1,
    unsigned* __restrict__ hpack0,    // [T+1][B][H] tagged, block 0 zeroed
    unsigned* __restrict__ hpack1,    // [T+1][B][H] tagged, block 0 zeroed
    unsigned* __restrict__ flags)     // [2][T+1][4][32] step flags (zeroed)
{
    __shared__ short Ra_hi[32][HP2], Ra_lo[32][HP2];   // recurrent h tile
    __shared__ short Xa_hi[32][HP2], Xa_lo[32][HP2];   // X-input tile (h0 or x)
    __shared__ float GsR[64][33];
    __shared__ float GsX[64][33];

    const int tid  = threadIdx.x;          // 0..511
    const int lane = tid & 63;
    const int wv   = tid >> 6;             // 0..7
    const bool isR = wv < 4;               // R-pipeline waves
    const int gate = wv & 3;               // gate for MFMA (both roles)
    const bool isB = blockIdx.x >= 128;
    const int blk  = blockIdx.x & 127;
    const int bt   = blk & 3;
    const int jsl  = blk >> 2;             // producer j-slice id 0..31
    const int j0   = jsl * 16;             // 16-unit slice
    const int l15  = lane & 15;
    const int quad = lane >> 4;
    const int tid_x = tid - 256;           // X-thread linear id (valid if !isR)

    // ---- preload weight frags: ONE array per thread, role-dependent.
    //      CONSTANT-BOUND unrolled loops in every branch (no scratch). ----
    bf16x8 wf_hi[16], wf_lo[16];
    if (isR) {
        const float* wsrc = isB ? w_hh1 : w_hh0;
        load_wfrag<16>(wsrc + (size_t)(gate * HH + j0 + l15) * HH + quad * 8,
                       wf_hi, wf_lo);
    } else if (isB) {
        load_wfrag<16>(w_ih1 + (size_t)(gate * HH + j0 + l15) * HH + quad * 8,
                       wf_hi, wf_lo);
    } else {
        load_wfrag<8>(w_ih0 + (size_t)(gate * HH + j0 + l15) * IND + quad * 8,
                      wf_hi, wf_lo);
    }

    // update-phase roles (R-threads): cells (j_u, bu) and (j_u, bu+16)
    const int j_u = tid & 15;
    const int bu  = (tid >> 4) & 15;       // 0..15
    float bias_i = 0.f, bias_f = 0.f, bias_g = 0.f, bias_o = 0.f;
    if (isR) {
        const float* bA = isB ? b_ih1 : b_ih0;
        const float* bB = isB ? b_hh1 : b_hh0;
        bias_i = bA[j0 + j_u]            + bB[j0 + j_u];
        bias_f = bA[HH + j0 + j_u]       + bB[HH + j0 + j_u];
        bias_g = bA[2 * HH + j0 + j_u]   + bB[2 * HH + j0 + j_u];
        bias_o = bA[3 * HH + j0 + j_u]   + bB[3 * HH + j0 + j_u];
    }

    unsigned* hp_rec = isB ? hpack1 : hpack0;
    const int layerBase = isB ? 65 : 0;
    float c0 = 0.f, c1 = 0.f;

    for (int t = 0; t < TT; ++t) {
        const unsigned* rec_base = hp_rec + (size_t)t * (BB * HH) + (size_t)bt * 32 * HH;
        const unsigned* inp_base = hpack0 + (size_t)(t + 1) * (BB * HH) + (size_t)bt * 32 * HH;
        const unsigned expR = (unsigned)t % 9u;
        const unsigned expX = (unsigned)(t + 1) % 9u;
        const unsigned* fR = flags + ((layerBase + t) * 4 + bt) * 32;
        const unsigned* fX = flags + ((t + 1) * 4 + bt) * 32;

        // ---- polls: wave 0 -> 32 R-flags; wave 4 -> 32 X-flags (layer 1).
        //      Layer-0's X input x[t] is a plain kernel input: no poll. ----
        if (wv == 0 && lane < 32 && t > 0 && lane != jsl) spin_flag(fR + lane);
        if (isB && wv == 4 && lane < 32) spin_flag(fX + lane);
        __syncthreads();                                   // B1

        // ---- staging ----
        if (isR) {
            stage_tile_g(rec_base, expR, tid * 8, 8, 2048, Ra_hi, Ra_lo);
        } else if (isB) {
            stage_tile_g(inp_base, expX, tid_x * 8, 8, 2048, Xa_hi, Xa_lo);
        } else {
            // layer-0 X: stage x[t] (32 rows x 256 fp32) as split-bf16.
            // No tags (plain input data). 256 threads x 32 values each.
            const int row = tid_x >> 3;
            const int cb  = (tid_x & 7) * 32;
            const float* src = x + (size_t)t * (BB * IND)
                             + (size_t)(bt * 32 + row) * IND + cb;
            #pragma unroll
            for (int q = 0; q < 4; ++q) {
                float f[8];
                *(float4*)&f[0] = *(const float4*)&src[q * 8];
                *(float4*)&f[4] = *(const float4*)&src[q * 8 + 4];
                short hs[8], ls[8];
                #pragma unroll
                for (int j = 0; j < 8; ++j) {
                    unsigned short hb = f2bf(f[j]);
                    hs[j] = (short)hb;
                    ls[j] = (short)f2bf(f[j] - bf2f(hb));
                }
                *(uint4*)&Xa_hi[row][cb + q * 8] = *(const uint4*)hs;
                *(uint4*)&Xa_lo[row][cb + q * 8] = *(const uint4*)ls;
            }
        }
        __syncthreads();                                   // B2

        // ---- MFMA + Gs writes (constant-bound sweeps in every branch) ----
        if (isR) {
            floatx4 a0 = {0.f,0.f,0.f,0.f}, a1 = {0.f,0.f,0.f,0.f};
            mfma_sweep<16>(wf_hi, wf_lo, Ra_hi, Ra_lo, l15, quad, a0, a1);
            #pragma unroll
            for (int r = 0; r < 4; ++r) {
                GsR[gate * 16 + quad * 4 + r][l15]      = a0[r];
                GsR[gate * 16 + quad * 4 + r][16 + l15] = a1[r];
            }
        } else {
            floatx4 a0 = {0.f,0.f,0.f,0.f}, a1 = {0.f,0.f,0.f,0.f};
            if (isB) mfma_sweep<16>(wf_hi, wf_lo, Xa_hi, Xa_lo, l15, quad, a0, a1);
            else     mfma_sweep<8> (wf_hi, wf_lo, Xa_hi, Xa_lo, l15, quad, a0, a1);
            #pragma unroll
            for (int r = 0; r < 4; ++r) {
                GsX[gate * 16 + quad * 4 + r][l15]      = a0[r];
                GsX[gate * 16 + quad * 4 + r][16 + l15] = a1[r];
            }
        }
        __syncthreads();                                   // B3

        // ---- update (R-threads): 2 cells; tagged per-cell 4B stores ----
        if (isR) {
            const unsigned tag = (unsigned)(t + 1) % 9u;
            #pragma unroll
            for (int ccell = 0; ccell < 2; ++ccell) {
                const int b = bu + ccell * 16;
                float gi = GsR[j_u][b]      + GsX[j_u][b]      + bias_i;
                float gf = GsR[16 + j_u][b] + GsX[16 + j_u][b] + bias_f;
                float gg = GsR[32 + j_u][b] + GsX[32 + j_u][b] + bias_g;
                float go = GsR[48 + j_u][b] + GsX[48 + j_u][b] + bias_o;
                const float si = 1.f / (1.f + __expf(-gi));
                const float sf = 1.f / (1.f + __expf(-gf));
                const float tg = 2.f / (1.f + __expf(-2.f * gg)) - 1.f;
                const float so = 1.f / (1.f + __expf(-go));
                float& cr = ccell ? c1 : c0;
                cr = sf * cr + si * tg;
                const float th = 2.f / (1.f + __expf(-2.f * cr)) - 1.f;
                const float hval = so * th;
                const unsigned short hb = f2bf(hval);
                const unsigned short lb = f2bf(hval - bf2f(hb));
                const unsigned pk = ((unsigned)hb << 16) | ((unsigned)lb & 0xFFF0u) | tag;
                __hip_atomic_store(
                    &hp_rec[(size_t)(t + 1) * (BB * HH) + (size_t)(bt * 32 + b) * HH + j0 + j_u],
                    pk, __ATOMIC_RELAXED, __HIP_MEMORY_SCOPE_AGENT);
            }
        }
        __syncthreads();                                   // B4 (drains stores)

        // ---- publish: single flag store for this slice (R5-proven) ----
        if (tid == 0)
            __hip_atomic_store(
                flags + ((layerBase + (t + 1)) * 4 + bt) * 32 + jsl,
                1u, __ATOMIC_RELAXED, __HIP_MEMORY_SCOPE_AGENT);
    }
}

// ---------------------------------------------------------------------------
// Classifier split-K partial GEMM on tagged h cells (mask tag nibble)
// ---------------------------------------------------------------------------
__global__ __launch_bounds__(256) void cls_partial_kernel(
    const unsigned* __restrict__ A, const float* __restrict__ W,
    float* __restrict__ part)
{
    const int n0 = blockIdx.x * 64;
    const int s  = blockIdx.y;
    const int kbase = s * 2048;
    const int tid = threadIdx.x;
    __shared__ float As[32][68];
    __shared__ float Bs[32][68];
    const int tm = tid >> 4, tn = tid & 15;
    float acc[4][4] = {};

    for (int kt = 0; kt < 2048; kt += 32) {
        #pragma unroll
        for (int q = tid; q < 512; q += 256) {
            const int mm = q >> 3;
            const int kq = q & 7;
            uint4 v = *(const uint4*)&A[(size_t)mm * KFLAT + kbase + kt + kq * 4];
            As[kq*4+0][mm] = pk2f(v.x & 0xFFFFFFF0u); As[kq*4+1][mm] = pk2f(v.y & 0xFFFFFFF0u);
            As[kq*4+2][mm] = pk2f(v.z & 0xFFFFFFF0u); As[kq*4+3][mm] = pk2f(v.w & 0xFFFFFFF0u);
            float4 w = *(const float4*)&W[(size_t)(n0 + mm) * KFLAT + kbase + kt + kq * 4];
            Bs[kq*4+0][mm] = w.x; Bs[kq*4+1][mm] = w.y;
            Bs[kq*4+2][mm] = w.z; Bs[kq*4+3][mm] = w.w;
        }
        __syncthreads();
        #pragma unroll
        for (int k = 0; k < 32; ++k) {
            float4 a = *(const float4*)&As[k][tm * 4];
            float4 b = *(const float4*)&Bs[k][tn * 4];
            acc[0][0] += a.x*b.x; acc[0][1] += a.x*b.y; acc[0][2] += a.x*b.z; acc[0][3] += a.x*b.w;
            acc[1][0] += a.y*b.x; acc[1][1] += a.y*b.y; acc[1][2] += a.y*b.z; acc[1][3] += a.y*b.w;
            acc[2][0] += a.z*b.x; acc[2][1] += a.z*b.y; acc[2][2] += a.z*b.z; acc[2][3] += a.z*b.w;
            acc[3][0] += a.w*b.x; acc[3][1] += a.w*b.y; acc[3][2] += a.w*b.z; acc[3][3] += a.w*b.w;
        }
        __syncthreads();
    }
    #pragma unroll
    for (int i = 0; i < 4; ++i) {
        const int m = tm * 4 + i;
        #pragma unroll
        for (int j = 0; j < 4; ++j) {
            part[((size_t)s * 64 + m) * 512 + n0 + tn * 4 + j] = acc[i][j];
        }
    }
}

// ---------------------------------------------------------------------------
// Classifier finish (unchanged)
// ---------------------------------------------------------------------------
__global__ __launch_bounds__(256) void cls_final_kernel(
    const float* __restrict__ part, const float* __restrict__ b1,
    const float* __restrict__ w2, const float* __restrict__ b2,
    float* __restrict__ out)
{
    const int t = blockIdx.x;
    __shared__ float hm[512];
    for (int n = threadIdx.x; n < 512; n += 256) {
        float sacc = b1[n];
        for (int sl = 0; sl < 32; ++sl)
            sacc += part[((size_t)sl * 64 + t) * 512 + n];
        hm[n] = fmaxf(sacc, 0.f);
    }
    __syncthreads();
    if (threadIdx.x < NCC) {
        float sacc = b2[threadIdx.x];
        const float* wr = w2 + (size_t)threadIdx.x * 512;
        for (int n = 0; n < 512; ++n) sacc += hm[n] * wr[n];
        out[t * NCC + threadIdx.x] = sacc;
    }
}

// ---------------------------------------------------------------------------
extern "C" void kernel_launch(void* const* d_in, const int* in_sizes, int n_in,
                              void* d_out, int out_size, void* d_ws, size_t ws_size,
                              hipStream_t stream)
{
    const float* x     = (const float*)d_in[0];
    const float* w_ih0 = (const float*)d_in[1];
    const float* w_hh0 = (const float*)d_in[2];
    const float* b_ih0 = (const float*)d_in[3];
    const float* b_hh0 = (const float*)d_in[4];
    const float* w_ih1 = (const float*)d_in[5];
    const float* w_hh1 = (const float*)d_in[6];
    const float* b_ih1 = (const float*)d_in[7];
    const float* b_hh1 = (const float*)d_in[8];
    const float* w1    = (const float*)d_in[9];
    const float* b1    = (const float*)d_in[10];
    const float* w2    = (const float*)d_in[11];
    const float* b2    = (const float*)d_in[12];
    float* out = (float*)d_out;

    // Workspace (~38.1 MB): the entire xg/xpk/w0pk precompute path is gone
    // (layer-0 input GEMM fused into lstm_fused's X-waves). All t>=1 h
    // reads are flag-gated (flags zeroed each launch) and tag-checked.
    // flags alias the part region (part written only after lstm_fused).
    unsigned* hpack0 = (unsigned*)d_ws;                         // 17.04 MB
    unsigned* hpack1 = hpack0 + (size_t)65 * BB * HH;           // 17.04 MB
    float*    part   = (float*)(hpack1 + (size_t)65 * BB * HH); // 4 MB
    unsigned* flags  = (unsigned*)part;                         // 66.6 KB (dies at cls)

    // ---- init: t=0 h blocks (tag 0 == 0%9 matches) + flags ----
    hipMemsetAsync(hpack0, 0, (size_t)BB * HH * sizeof(unsigned), stream);
    hipMemsetAsync(hpack1, 0, (size_t)BB * HH * sizeof(unsigned), stream);
    hipMemsetAsync(flags, 0, (size_t)2 * 65 * 4 * 32 * sizeof(unsigned), stream);

    // ---- fused two-layer recurrence (input GEMM folded in) ----
    lstm_fused<<<256, 512, 0, stream>>>(
        x, w_hh0, w_ih0, w_ih1, w_hh1, b_ih0, b_hh0, b_ih1, b_hh1,
        hpack0, hpack1, flags);

    // ---- classifier (tagged h1, blocks 1..64) ----
    cls_partial_kernel<<<dim3(512 / 64, 32), 256, 0, stream>>>(
        hpack1 + (size_t)BB * HH, w1, part);
    cls_final_kernel<<<64, 256, 0, stream>>>(part, b1, w2, b2, out);
}